// Round 2
// baseline (506.596 us; speedup 1.0000x reference)
//
#include <hip/hip_runtime.h>
#include <hip/hip_bf16.h>

typedef __bf16 bf16x8 __attribute__((ext_vector_type(8)));
typedef float  f32x4  __attribute__((ext_vector_type(4)));

#define SCALE_QK 0.17677669529663687f   // 1/sqrt(32)
#define LDSS 40                          // LDS leading stride (elems): 80B rows -> 2-way bank aliasing (free)

__device__ __forceinline__ float b2f(ushort u) {
    __hip_bfloat16 h; *reinterpret_cast<ushort*>(&h) = u; return __bfloat162float(h);
}
__device__ __forceinline__ ushort f2b(float f) {
    __hip_bfloat16 h = __float2bfloat16(f); return *reinterpret_cast<ushort*>(&h);
}

// ---------------------------------------------------------------------------
// K0: weight prep (all weights are fp32 in HBM).
//  Wq,Wk (512x128) -> transposed hi/lo bf16 (128x512 each)
//  Wv (512x128)    -> transposed bf16 (128x512)
//  Wqo (128x512)   -> transposed bf16 (512x128)
//  Wo (128x512)    -> bf16 copy (no transpose)
// ---------------------------------------------------------------------------
__global__ void k_prep(const float* __restrict__ Wq, const float* __restrict__ Wk,
                       const float* __restrict__ Wv, const float* __restrict__ Wqo,
                       const float* __restrict__ Wo,
                       ushort* __restrict__ WqThi, ushort* __restrict__ WqTlo,
                       ushort* __restrict__ WkThi, ushort* __restrict__ WkTlo,
                       ushort* __restrict__ WvT,  ushort* __restrict__ WqoT,
                       ushort* __restrict__ WoB) {
    int idx = blockIdx.x * 256 + threadIdx.x;   // 5 * 65536 total
    int mat = idx >> 16, i = idx & 65535;
    if (mat == 0) {
        int n = i >> 9, k = i & 511;
        float w = Wq[k * 128 + n];
        ushort hi = f2b(w);
        WqThi[i] = hi; WqTlo[i] = f2b(w - b2f(hi));
    } else if (mat == 1) {
        int n = i >> 9, k = i & 511;
        float w = Wk[k * 128 + n];
        ushort hi = f2b(w);
        WkThi[i] = hi; WkTlo[i] = f2b(w - b2f(hi));
    } else if (mat == 2) {
        int n = i >> 9, k = i & 511;
        WvT[i] = f2b(Wv[k * 128 + n]);
    } else if (mat == 3) {
        int n = i >> 7, k = i & 127;
        WqoT[i] = f2b(Wqo[k * 512 + n]);
    } else if (mat == 4) {
        WoB[i] = f2b(Wo[i]);
    }
}

// ---------------------------------------------------------------------------
// K1: split-bf16 projection GEMM (high precision; feeds the L=4096 score
// reduction).  C(Mx128) = A_f32(Mx512) @ B(512x128) + bias, with A,B each
// decomposed hi+lo bf16; acc += aH*bH + aH*bL + aL*bH  (rel err ~2^-17).
// 128x128 tile, 4 waves (2x2), 16x16x32 bf16 MFMA, BK=32.
// ---------------------------------------------------------------------------
__global__ __launch_bounds__(256) void k_proj_split(
        const float* __restrict__ A, const ushort* __restrict__ BThi,
        const ushort* __restrict__ BTlo, const float* __restrict__ bias,
        float* __restrict__ outF, ushort* __restrict__ outB) {
    __shared__ __align__(16) ushort AsH[128 * LDSS], AsL[128 * LDSS];
    __shared__ __align__(16) ushort BsH[128 * LDSS], BsL[128 * LDSS];
    const int row0 = blockIdx.x * 128;
    const int tid  = threadIdx.x;
    const int wid  = tid >> 6, lane = tid & 63;
    const int wm = wid >> 1, wn = wid & 1;
    const int quad = lane >> 4, l16 = lane & 15;
    const int sr = tid >> 2;            // staging row 0..63 (two passes)
    const int sc = (tid & 3) * 8;       // staging col 0,8,16,24

    f32x4 acc[4][4] = {};

    for (int k0 = 0; k0 < 512; k0 += 32) {
        __syncthreads();
#pragma unroll
        for (int p = 0; p < 2; ++p) {
            int r = sr + p * 64;
            float4 a0 = *(const float4*)&A[(size_t)(row0 + r) * 512 + k0 + sc];
            float4 a1 = *(const float4*)&A[(size_t)(row0 + r) * 512 + k0 + sc + 4];
            float av[8] = {a0.x, a0.y, a0.z, a0.w, a1.x, a1.y, a1.z, a1.w};
            union { uint4 v; ushort u[8]; } H, L;
#pragma unroll
            for (int i = 0; i < 8; ++i) {
                ushort hi = f2b(av[i]);
                H.u[i] = hi;
                L.u[i] = f2b(av[i] - b2f(hi));
            }
            *(uint4*)&AsH[r * LDSS + sc] = H.v;
            *(uint4*)&AsL[r * LDSS + sc] = L.v;
            uint4 bh = *(const uint4*)&BThi[(size_t)r * 512 + k0 + sc];
            uint4 bl = *(const uint4*)&BTlo[(size_t)r * 512 + k0 + sc];
            *(uint4*)&BsH[r * LDSS + sc] = bh;
            *(uint4*)&BsL[r * LDSS + sc] = bl;
        }
        __syncthreads();
        bf16x8 aH[4], aL[4], bH[4], bL[4];
#pragma unroll
        for (int i = 0; i < 4; ++i) {
            int ro = (wm * 64 + i * 16 + l16) * LDSS + quad * 8;
            aH[i] = *reinterpret_cast<const bf16x8*>(&AsH[ro]);
            aL[i] = *reinterpret_cast<const bf16x8*>(&AsL[ro]);
        }
#pragma unroll
        for (int j = 0; j < 4; ++j) {
            int ro = (wn * 64 + j * 16 + l16) * LDSS + quad * 8;
            bH[j] = *reinterpret_cast<const bf16x8*>(&BsH[ro]);
            bL[j] = *reinterpret_cast<const bf16x8*>(&BsL[ro]);
        }
#pragma unroll
        for (int i = 0; i < 4; ++i)
#pragma unroll
            for (int j = 0; j < 4; ++j) {
                acc[i][j] = __builtin_amdgcn_mfma_f32_16x16x32_bf16(aL[i], bH[j], acc[i][j], 0, 0, 0);
                acc[i][j] = __builtin_amdgcn_mfma_f32_16x16x32_bf16(aH[i], bL[j], acc[i][j], 0, 0, 0);
                acc[i][j] = __builtin_amdgcn_mfma_f32_16x16x32_bf16(aH[i], bH[j], acc[i][j], 0, 0, 0);
            }
    }

    // epilogue: D row = quad*4 + reg, col = l16 (verified C/D mapping)
#pragma unroll
    for (int i = 0; i < 4; ++i)
#pragma unroll
        for (int j = 0; j < 4; ++j) {
            int ncol = wn * 64 + j * 16 + l16;
            float bv = bias[ncol];
#pragma unroll
            for (int r = 0; r < 4; ++r) {
                int mrow = row0 + wm * 64 + i * 16 + quad * 4 + r;
                float v = acc[i][j][r] + bv;
                if (outF) outF[(size_t)mrow * 128 + ncol] = v;
                if (outB) outB[(size_t)mrow * 128 + ncol] = f2b(v);
            }
        }
}

// ---------------------------------------------------------------------------
// K1b: plain bf16 projection (Vm).  A fp32 -> bf16 at staging.
// ---------------------------------------------------------------------------
__global__ __launch_bounds__(256) void k_proj_plain(
        const float* __restrict__ A, const ushort* __restrict__ BT,
        const float* __restrict__ bias, ushort* __restrict__ outB) {
    __shared__ __align__(16) ushort As[128 * LDSS];
    __shared__ __align__(16) ushort Bs[128 * LDSS];
    const int row0 = blockIdx.x * 128;
    const int tid  = threadIdx.x;
    const int wid  = tid >> 6, lane = tid & 63;
    const int wm = wid >> 1, wn = wid & 1;
    const int quad = lane >> 4, l16 = lane & 15;
    const int sr = tid >> 2;
    const int sc = (tid & 3) * 8;

    f32x4 acc[4][4] = {};

    for (int k0 = 0; k0 < 512; k0 += 32) {
        __syncthreads();
#pragma unroll
        for (int p = 0; p < 2; ++p) {
            int r = sr + p * 64;
            float4 a0 = *(const float4*)&A[(size_t)(row0 + r) * 512 + k0 + sc];
            float4 a1 = *(const float4*)&A[(size_t)(row0 + r) * 512 + k0 + sc + 4];
            float av[8] = {a0.x, a0.y, a0.z, a0.w, a1.x, a1.y, a1.z, a1.w};
            union { uint4 v; ushort u[8]; } H;
#pragma unroll
            for (int i = 0; i < 8; ++i) H.u[i] = f2b(av[i]);
            *(uint4*)&As[r * LDSS + sc] = H.v;
            *(uint4*)&Bs[r * LDSS + sc] = *(const uint4*)&BT[(size_t)r * 512 + k0 + sc];
        }
        __syncthreads();
        bf16x8 aF[4], bF[4];
#pragma unroll
        for (int i = 0; i < 4; ++i)
            aF[i] = *reinterpret_cast<const bf16x8*>(&As[(wm * 64 + i * 16 + l16) * LDSS + quad * 8]);
#pragma unroll
        for (int j = 0; j < 4; ++j)
            bF[j] = *reinterpret_cast<const bf16x8*>(&Bs[(wn * 64 + j * 16 + l16) * LDSS + quad * 8]);
#pragma unroll
        for (int i = 0; i < 4; ++i)
#pragma unroll
            for (int j = 0; j < 4; ++j)
                acc[i][j] = __builtin_amdgcn_mfma_f32_16x16x32_bf16(aF[i], bF[j], acc[i][j], 0, 0, 0);
    }

#pragma unroll
    for (int i = 0; i < 4; ++i)
#pragma unroll
        for (int j = 0; j < 4; ++j) {
            int ncol = wn * 64 + j * 16 + l16;
            float bv = bias[ncol];
#pragma unroll
            for (int r = 0; r < 4; ++r) {
                int mrow = row0 + wm * 64 + i * 16 + quad * 4 + r;
                outB[(size_t)mrow * 128 + ncol] = f2b(acc[i][j][r] + bv);
            }
        }
}

// ---------------------------------------------------------------------------
// K2: score partials, fp32 VALU.
// partial[sp][b*4+h][d][e] = sum_{l in split of 128} Qm[l][hd]*Km[l][he]
// grid (16 b, 32 splits), 256 threads; thread owns a 4x4 (d,e) of one head.
// ---------------------------------------------------------------------------
__global__ __launch_bounds__(256) void k_scores(
        const float* __restrict__ Qm, const float* __restrict__ Km,
        float* __restrict__ partial) {
    int b = blockIdx.x, sp = blockIdx.y;
    int t = threadIdx.x;
    int h = t >> 6, tl = t & 63;
    int d0 = (tl >> 3) * 4, e0 = (tl & 7) * 4;
    const float* Qb = Qm + ((size_t)b * 4096 + sp * 128) * 128 + h * 32 + d0;
    const float* Kb = Km + ((size_t)b * 4096 + sp * 128) * 128 + h * 32 + e0;
    float acc[4][4] = {};
#pragma unroll 4
    for (int l = 0; l < 128; ++l) {
        float4 q4 = *(const float4*)(Qb + (size_t)l * 128);
        float4 k4 = *(const float4*)(Kb + (size_t)l * 128);
        float q[4] = {q4.x, q4.y, q4.z, q4.w};
        float k[4] = {k4.x, k4.y, k4.z, k4.w};
#pragma unroll
        for (int i = 0; i < 4; ++i)
#pragma unroll
            for (int j = 0; j < 4; ++j) acc[i][j] += q[i] * k[j];
    }
    float* P = partial + ((size_t)(sp * 64 + b * 4 + h)) * 1024;
#pragma unroll
    for (int i = 0; i < 4; ++i)
#pragma unroll
        for (int j = 0; j < 4; ++j)
            P[(d0 + i) * 32 + e0 + j] = acc[i][j];
}

// ---------------------------------------------------------------------------
// K3a: reduce partials + softmax over e.  One block per (b,h), 32x32 threads.
// Writes attn fp32 straight into d_out tail (reference output 1).
// ---------------------------------------------------------------------------
__global__ __launch_bounds__(1024) void k_softmax(
        const float* __restrict__ partial, float* __restrict__ attnOut) {
    int bh = blockIdx.x;
    int e = threadIdx.x;   // 0..31
    int d = threadIdx.y;   // 0..31
    float s = 0.f;
#pragma unroll
    for (int sp = 0; sp < 32; ++sp)
        s += partial[((size_t)(sp * 64 + bh)) * 1024 + d * 32 + e];
    s *= SCALE_QK;
    float m = s;
    for (int off = 16; off; off >>= 1) m = fmaxf(m, __shfl_xor(m, off, 32));
    float p = __expf(s - m);
    float sum = p;
    for (int off = 16; off; off >>= 1) sum += __shfl_xor(sum, off, 32);
    p /= sum;
    attnOut[(size_t)bh * 1024 + d * 32 + e] = p;
}

// ---------------------------------------------------------------------------
// K3b: WcT[b][m][h*32+e] = sum_d attn[b,h,d,e] * Wo[h*32+d][m]   (bf16 out)
// One block per (b,h); Wo head-slab (32x512 bf16) + attn (32x32 f32) in LDS.
// ---------------------------------------------------------------------------
__global__ __launch_bounds__(256) void k_wc(
        const float* __restrict__ attnF, const ushort* __restrict__ WoB,
        ushort* __restrict__ WcT) {
    int b = blockIdx.x >> 2, h = blockIdx.x & 3;
    __shared__ float aS[32 * 32];
    __shared__ __align__(16) ushort wS[32 * 512];
    int t = threadIdx.x;
    for (int i = t; i < 1024; i += 256)
        aS[i] = attnF[((size_t)(b * 4 + h)) * 1024 + i];
    for (int i = t; i < 2048; i += 256) {
        int r = i >> 6, c = (i & 63) * 8;
        *(uint4*)&wS[r * 512 + c] = *(const uint4*)&WoB[(size_t)(h * 32 + r) * 512 + c];
    }
    __syncthreads();
    int e = t & 31;
    int mg = t >> 5;
    for (int mi = 0; mi < 64; ++mi) {
        int m = mg * 64 + mi;
        float acc = 0.f;
#pragma unroll
        for (int d = 0; d < 32; ++d)
            acc += aS[d * 32 + e] * b2f(wS[d * 512 + m]);
        WcT[((size_t)b * 512 + m) * 128 + h * 32 + e] = f2b(acc);
    }
}

// ---------------------------------------------------------------------------
// K4a: x = Vm @ Wc_b + Qm @ Wqo + (bo + bqo), fp32 into d_out (pre-LN).
// K=256 concat: k<128 -> (Vm, WcT_b), k>=128 -> (Qm, WqoT).
// grid (4 col-blocks, 512 row-blocks) -> consecutive blocks share A tile (L2).
// ---------------------------------------------------------------------------
__global__ __launch_bounds__(256) void k_out_gemm(
        const ushort* __restrict__ Vm, const ushort* __restrict__ Qm,
        const ushort* __restrict__ WcT, const ushort* __restrict__ WqoT,
        const float* __restrict__ bo, const float* __restrict__ bqo,
        float* __restrict__ X) {
    __shared__ __align__(16) ushort As[128 * LDSS];
    __shared__ __align__(16) ushort Bs[128 * LDSS];
    const int col0 = blockIdx.x * 128;
    const int row0 = blockIdx.y * 128;
    const int b = row0 >> 12;
    const ushort* WcTb = WcT + (size_t)b * 512 * 128;
    const int tid = threadIdx.x;
    const int wid = tid >> 6, lane = tid & 63;
    const int wm = wid >> 1, wn = wid & 1;
    const int quad = lane >> 4, l16 = lane & 15;
    const int sr = tid >> 2;
    const int sc = (tid & 3) * 8;

    f32x4 acc[4][4] = {};

    for (int k0 = 0; k0 < 256; k0 += 32) {
        const ushort* Asrc; const ushort* Bsrc; int kk;
        if (k0 < 128) { Asrc = Vm; Bsrc = WcTb; kk = k0; }
        else          { Asrc = Qm; Bsrc = WqoT; kk = k0 - 128; }
        __syncthreads();
#pragma unroll
        for (int p = 0; p < 2; ++p) {
            int r = sr + p * 64;
            uint4 va = *(const uint4*)&Asrc[(size_t)(row0 + r) * 128 + kk + sc];
            uint4 vb = *(const uint4*)&Bsrc[(size_t)(col0 + r) * 128 + kk + sc];
            *(uint4*)&As[r * LDSS + sc] = va;
            *(uint4*)&Bs[r * LDSS + sc] = vb;
        }
        __syncthreads();
        bf16x8 aF[4], bF[4];
#pragma unroll
        for (int i = 0; i < 4; ++i)
            aF[i] = *reinterpret_cast<const bf16x8*>(&As[(wm * 64 + i * 16 + l16) * LDSS + quad * 8]);
#pragma unroll
        for (int j = 0; j < 4; ++j)
            bF[j] = *reinterpret_cast<const bf16x8*>(&Bs[(wn * 64 + j * 16 + l16) * LDSS + quad * 8]);
#pragma unroll
        for (int i = 0; i < 4; ++i)
#pragma unroll
            for (int j = 0; j < 4; ++j)
                acc[i][j] = __builtin_amdgcn_mfma_f32_16x16x32_bf16(aF[i], bF[j], acc[i][j], 0, 0, 0);
    }

#pragma unroll
    for (int i = 0; i < 4; ++i)
#pragma unroll
        for (int j = 0; j < 4; ++j) {
            int ncol = col0 + wn * 64 + j * 16 + l16;
            float bv = bo[ncol] + bqo[ncol];
#pragma unroll
            for (int r = 0; r < 4; ++r) {
                int mrow = row0 + wm * 64 + i * 16 + quad * 4 + r;
                X[(size_t)mrow * 512 + ncol] = acc[i][j][r] + bv;
            }
        }
}

// ---------------------------------------------------------------------------
// K4b: in-place fp32 LayerNorm over 512 cols.  One wave per row, 8 cols/lane.
// ---------------------------------------------------------------------------
__global__ __launch_bounds__(256) void k_ln(
        float* __restrict__ Y, const float* __restrict__ gamma,
        const float* __restrict__ beta) {
    int row = blockIdx.x * 4 + (threadIdx.x >> 6);
    int lane = threadIdx.x & 63;
    size_t base = (size_t)row * 512 + lane * 8;
    float4 v0 = *(const float4*)&Y[base];
    float4 v1 = *(const float4*)&Y[base + 4];
    float x[8] = {v0.x, v0.y, v0.z, v0.w, v1.x, v1.y, v1.z, v1.w};
    float s = 0.f, ss = 0.f;
#pragma unroll
    for (int i = 0; i < 8; ++i) { s += x[i]; ss += x[i] * x[i]; }
    for (int off = 32; off; off >>= 1) {
        s  += __shfl_xor(s,  off, 64);
        ss += __shfl_xor(ss, off, 64);
    }
    float mu = s * (1.f / 512.f);
    float var = ss * (1.f / 512.f) - mu * mu;
    float rstd = rsqrtf(var + 1e-5f);
    float4 g0 = *(const float4*)&gamma[lane * 8];
    float4 g1 = *(const float4*)&gamma[lane * 8 + 4];
    float4 b0 = *(const float4*)&beta[lane * 8];
    float4 b1 = *(const float4*)&beta[lane * 8 + 4];
    float g[8] = {g0.x, g0.y, g0.z, g0.w, g1.x, g1.y, g1.z, g1.w};
    float bt[8] = {b0.x, b0.y, b0.z, b0.w, b1.x, b1.y, b1.z, b1.w};
    float4 o0, o1;
    float* o = (float*)&o0;   // o0,o1 contiguous writes below
#pragma unroll
    for (int i = 0; i < 4; ++i) ((float*)&o0)[i] = (x[i] - mu) * rstd * g[i] + bt[i];
#pragma unroll
    for (int i = 0; i < 4; ++i) ((float*)&o1)[i] = (x[i + 4] - mu) * rstd * g[i + 4] + bt[i + 4];
    (void)o;
    *(float4*)&Y[base] = o0;
    *(float4*)&Y[base + 4] = o1;
}

// ---------------------------------------------------------------------------
extern "C" void kernel_launch(void* const* d_in, const int* in_sizes, int n_in,
                              void* d_out, int out_size, void* d_ws, size_t ws_size,
                              hipStream_t stream) {
    const float* Qin   = (const float*)d_in[0];
    const float* KVin  = (const float*)d_in[1];
    const float* Wq    = (const float*)d_in[2];
    const float* bq    = (const float*)d_in[3];
    const float* Wk    = (const float*)d_in[4];
    const float* bk    = (const float*)d_in[5];
    const float* Wv    = (const float*)d_in[6];
    const float* bv    = (const float*)d_in[7];
    const float* Wo    = (const float*)d_in[8];
    const float* bo    = (const float*)d_in[9];
    const float* Wqo   = (const float*)d_in[10];
    const float* bqo   = (const float*)d_in[11];
    const float* gamma = (const float*)d_in[12];
    const float* beta  = (const float*)d_in[13];
    float* out = (float*)d_out;           // [y (16*4096*512) | attn (16*4*32*32)]
    float* attnOut = out + 33554432;

    char* ws = (char*)d_ws;
    ushort* WqThi = (ushort*)(ws);
    ushort* WqTlo = (ushort*)(ws + 131072);
    ushort* WkThi = (ushort*)(ws + 262144);
    ushort* WkTlo = (ushort*)(ws + 393216);
    ushort* WvT   = (ushort*)(ws + 524288);
    ushort* WqoT  = (ushort*)(ws + 655360);
    ushort* WoB   = (ushort*)(ws + 786432);
    float*  QmF   = (float*) (ws + 917504);
    float*  KmF   = (float*) (ws + 34471936);
    ushort* QmB   = (ushort*)(ws + 68026368);
    ushort* VmB   = (ushort*)(ws + 84803584);
    float*  part  = (float*) (ws + 101580800);
    ushort* WcT   = (ushort*)(ws + 109969408);
    // total ws use: 112,066,560 bytes

    k_prep<<<1280, 256, 0, stream>>>(Wq, Wk, Wv, Wqo, Wo,
                                     WqThi, WqTlo, WkThi, WkTlo, WvT, WqoT, WoB);
    k_proj_split<<<512, 256, 0, stream>>>(Qin,  WqThi, WqTlo, bq, QmF, QmB);
    k_proj_split<<<512, 256, 0, stream>>>(KVin, WkThi, WkTlo, bk, KmF, nullptr);
    k_proj_plain<<<512, 256, 0, stream>>>(KVin, WvT, bv, VmB);
    k_scores<<<dim3(16, 32), 256, 0, stream>>>(QmF, KmF, part);
    k_softmax<<<64, dim3(32, 32), 0, stream>>>(part, attnOut);
    k_wc<<<64, 256, 0, stream>>>(attnOut, WoB, WcT);
    k_out_gemm<<<dim3(4, 512), 256, 0, stream>>>(VmB, QmB, WcT, WqoT, bo, bqo, out);
    k_ln<<<16384, 256, 0, stream>>>(out, gamma, beta);
}

// Round 3
// 485.935 us; speedup vs baseline: 1.0425x; 1.0425x over previous
//
#include <hip/hip_runtime.h>
#include <hip/hip_bf16.h>

typedef __bf16 bf16x8 __attribute__((ext_vector_type(8)));
typedef float  f32x4  __attribute__((ext_vector_type(4)));

#define SCALE_QK 0.17677669529663687f   // 1/sqrt(32)
#define LDSS 40                          // LDS leading stride: 80B rows -> 2-way bank aliasing (free)

__device__ __forceinline__ float b2f(ushort u) {
    __hip_bfloat16 h; *reinterpret_cast<ushort*>(&h) = u; return __bfloat162float(h);
}
__device__ __forceinline__ ushort f2b(float f) {
    __hip_bfloat16 h = __float2bfloat16(f); return *reinterpret_cast<ushort*>(&h);
}

// ---------------------------------------------------------------------------
// K0: weight prep (fp32 in HBM).
//  Wq,Wk (512x128) -> transposed hi/lo bf16 (128x512 each)
//  Wv (512x128)    -> transposed bf16 (128x512)
//  Wqo (128x512)   -> transposed bf16 (512x128)
//  Wo (128x512)    -> bf16 copy
// ---------------------------------------------------------------------------
__global__ void k_prep(const float* __restrict__ Wq, const float* __restrict__ Wk,
                       const float* __restrict__ Wv, const float* __restrict__ Wqo,
                       const float* __restrict__ Wo,
                       ushort* __restrict__ WqThi, ushort* __restrict__ WqTlo,
                       ushort* __restrict__ WkThi, ushort* __restrict__ WkTlo,
                       ushort* __restrict__ WvT,  ushort* __restrict__ WqoT,
                       ushort* __restrict__ WoB) {
    int idx = blockIdx.x * 256 + threadIdx.x;   // 5 * 65536 total
    int mat = idx >> 16, i = idx & 65535;
    if (mat == 0) {
        int n = i >> 9, k = i & 511;
        float w = Wq[k * 128 + n];
        ushort hi = f2b(w);
        WqThi[i] = hi; WqTlo[i] = f2b(w - b2f(hi));
    } else if (mat == 1) {
        int n = i >> 9, k = i & 511;
        float w = Wk[k * 128 + n];
        ushort hi = f2b(w);
        WkThi[i] = hi; WkTlo[i] = f2b(w - b2f(hi));
    } else if (mat == 2) {
        int n = i >> 9, k = i & 511;
        WvT[i] = f2b(Wv[k * 128 + n]);
    } else if (mat == 3) {
        int n = i >> 7, k = i & 127;
        WqoT[i] = f2b(Wqo[k * 512 + n]);
    } else if (mat == 4) {
        WoB[i] = f2b(Wo[i]);
    }
}

// ---------------------------------------------------------------------------
// K1: split-bf16 projection (Q).  C = A_f32 @ B + bias, A,B hi/lo bf16,
// acc += aL*bH + aH*bL + aH*bH  (rel err ~2^-17).  128x128 tile, BK=32.
// ---------------------------------------------------------------------------
__global__ __launch_bounds__(256) void k_proj_split(
        const float* __restrict__ A, const ushort* __restrict__ BThi,
        const ushort* __restrict__ BTlo, const float* __restrict__ bias,
        float* __restrict__ outF, ushort* __restrict__ outB) {
    __shared__ __align__(16) ushort AsH[128 * LDSS], AsL[128 * LDSS];
    __shared__ __align__(16) ushort BsH[128 * LDSS], BsL[128 * LDSS];
    const int row0 = blockIdx.x * 128;
    const int tid  = threadIdx.x;
    const int wid  = tid >> 6, lane = tid & 63;
    const int wm = wid >> 1, wn = wid & 1;
    const int quad = lane >> 4, l16 = lane & 15;
    const int sr = tid >> 2;
    const int sc = (tid & 3) * 8;

    f32x4 acc[4][4] = {};

    for (int k0 = 0; k0 < 512; k0 += 32) {
        __syncthreads();
#pragma unroll
        for (int p = 0; p < 2; ++p) {
            int r = sr + p * 64;
            float4 a0 = *(const float4*)&A[(size_t)(row0 + r) * 512 + k0 + sc];
            float4 a1 = *(const float4*)&A[(size_t)(row0 + r) * 512 + k0 + sc + 4];
            float av[8] = {a0.x, a0.y, a0.z, a0.w, a1.x, a1.y, a1.z, a1.w};
            union { uint4 v; ushort u[8]; } H, L;
#pragma unroll
            for (int i = 0; i < 8; ++i) {
                ushort hi = f2b(av[i]);
                H.u[i] = hi;
                L.u[i] = f2b(av[i] - b2f(hi));
            }
            *(uint4*)&AsH[r * LDSS + sc] = H.v;
            *(uint4*)&AsL[r * LDSS + sc] = L.v;
            *(uint4*)&BsH[r * LDSS + sc] = *(const uint4*)&BThi[(size_t)r * 512 + k0 + sc];
            *(uint4*)&BsL[r * LDSS + sc] = *(const uint4*)&BTlo[(size_t)r * 512 + k0 + sc];
        }
        __syncthreads();
        bf16x8 aH[4], aL[4];
#pragma unroll
        for (int i = 0; i < 4; ++i) {
            int ro = (wm * 64 + i * 16 + l16) * LDSS + quad * 8;
            aH[i] = *reinterpret_cast<const bf16x8*>(&AsH[ro]);
            aL[i] = *reinterpret_cast<const bf16x8*>(&AsL[ro]);
        }
#pragma unroll
        for (int j = 0; j < 4; ++j) {
            int ro = (wn * 64 + j * 16 + l16) * LDSS + quad * 8;
            bf16x8 bH = *reinterpret_cast<const bf16x8*>(&BsH[ro]);
            bf16x8 bL = *reinterpret_cast<const bf16x8*>(&BsL[ro]);
#pragma unroll
            for (int i = 0; i < 4; ++i) {
                acc[i][j] = __builtin_amdgcn_mfma_f32_16x16x32_bf16(aL[i], bH, acc[i][j], 0, 0, 0);
                acc[i][j] = __builtin_amdgcn_mfma_f32_16x16x32_bf16(aH[i], bL, acc[i][j], 0, 0, 0);
                acc[i][j] = __builtin_amdgcn_mfma_f32_16x16x32_bf16(aH[i], bH, acc[i][j], 0, 0, 0);
            }
        }
    }

#pragma unroll
    for (int i = 0; i < 4; ++i)
#pragma unroll
        for (int j = 0; j < 4; ++j) {
            int ncol = wn * 64 + j * 16 + l16;
            float bv = bias[ncol];
#pragma unroll
            for (int r = 0; r < 4; ++r) {
                int mrow = row0 + wm * 64 + i * 16 + quad * 4 + r;
                float v = acc[i][j][r] + bv;
                if (outF) outF[(size_t)mrow * 128 + ncol] = v;
                if (outB) outB[(size_t)mrow * 128 + ncol] = f2b(v);
            }
        }
}

// ---------------------------------------------------------------------------
// K2: fused K(split) + V(plain) projection — reads KVin ONCE.
// V's bf16 A-operand is exactly the hi part of the split decomposition.
// ---------------------------------------------------------------------------
__global__ __launch_bounds__(256) void k_proj_kv(
        const float* __restrict__ A,
        const ushort* __restrict__ BKhi, const ushort* __restrict__ BKlo,
        const ushort* __restrict__ BV,
        const float* __restrict__ biasK, const float* __restrict__ biasV,
        float* __restrict__ KmF, ushort* __restrict__ VmB) {
    __shared__ __align__(16) ushort AsH[128 * LDSS], AsL[128 * LDSS];
    __shared__ __align__(16) ushort BsKH[128 * LDSS], BsKL[128 * LDSS], BsV[128 * LDSS];
    const int row0 = blockIdx.x * 128;
    const int tid  = threadIdx.x;
    const int wid  = tid >> 6, lane = tid & 63;
    const int wm = wid >> 1, wn = wid & 1;
    const int quad = lane >> 4, l16 = lane & 15;
    const int sr = tid >> 2;
    const int sc = (tid & 3) * 8;

    f32x4 accK[4][4] = {};
    f32x4 accV[4][4] = {};

    for (int k0 = 0; k0 < 512; k0 += 32) {
        __syncthreads();
#pragma unroll
        for (int p = 0; p < 2; ++p) {
            int r = sr + p * 64;
            float4 a0 = *(const float4*)&A[(size_t)(row0 + r) * 512 + k0 + sc];
            float4 a1 = *(const float4*)&A[(size_t)(row0 + r) * 512 + k0 + sc + 4];
            float av[8] = {a0.x, a0.y, a0.z, a0.w, a1.x, a1.y, a1.z, a1.w};
            union { uint4 v; ushort u[8]; } H, L;
#pragma unroll
            for (int i = 0; i < 8; ++i) {
                ushort hi = f2b(av[i]);
                H.u[i] = hi;
                L.u[i] = f2b(av[i] - b2f(hi));
            }
            *(uint4*)&AsH[r * LDSS + sc] = H.v;
            *(uint4*)&AsL[r * LDSS + sc] = L.v;
            *(uint4*)&BsKH[r * LDSS + sc] = *(const uint4*)&BKhi[(size_t)r * 512 + k0 + sc];
            *(uint4*)&BsKL[r * LDSS + sc] = *(const uint4*)&BKlo[(size_t)r * 512 + k0 + sc];
            *(uint4*)&BsV [r * LDSS + sc] = *(const uint4*)&BV  [(size_t)r * 512 + k0 + sc];
        }
        __syncthreads();
        bf16x8 aH[4], aL[4];
#pragma unroll
        for (int i = 0; i < 4; ++i) {
            int ro = (wm * 64 + i * 16 + l16) * LDSS + quad * 8;
            aH[i] = *reinterpret_cast<const bf16x8*>(&AsH[ro]);
            aL[i] = *reinterpret_cast<const bf16x8*>(&AsL[ro]);
        }
#pragma unroll
        for (int j = 0; j < 4; ++j) {
            int ro = (wn * 64 + j * 16 + l16) * LDSS + quad * 8;
            bf16x8 bKH = *reinterpret_cast<const bf16x8*>(&BsKH[ro]);
            bf16x8 bKL = *reinterpret_cast<const bf16x8*>(&BsKL[ro]);
            bf16x8 bV  = *reinterpret_cast<const bf16x8*>(&BsV [ro]);
#pragma unroll
            for (int i = 0; i < 4; ++i) {
                accK[i][j] = __builtin_amdgcn_mfma_f32_16x16x32_bf16(aL[i], bKH, accK[i][j], 0, 0, 0);
                accK[i][j] = __builtin_amdgcn_mfma_f32_16x16x32_bf16(aH[i], bKL, accK[i][j], 0, 0, 0);
                accK[i][j] = __builtin_amdgcn_mfma_f32_16x16x32_bf16(aH[i], bKH, accK[i][j], 0, 0, 0);
                accV[i][j] = __builtin_amdgcn_mfma_f32_16x16x32_bf16(aH[i], bV,  accV[i][j], 0, 0, 0);
            }
        }
    }

#pragma unroll
    for (int i = 0; i < 4; ++i)
#pragma unroll
        for (int j = 0; j < 4; ++j) {
            int ncol = wn * 64 + j * 16 + l16;
            float bk = biasK[ncol], bv = biasV[ncol];
#pragma unroll
            for (int r = 0; r < 4; ++r) {
                int mrow = row0 + wm * 64 + i * 16 + quad * 4 + r;
                KmF[(size_t)mrow * 128 + ncol] = accK[i][j][r] + bk;
                VmB[(size_t)mrow * 128 + ncol] = f2b(accV[i][j][r] + bv);
            }
        }
}

// ---------------------------------------------------------------------------
// K3: score partials, fp32 VALU.
// partial[sp][b*4+h][d][e] = sum_{l in split of 128} Qm[l][hd]*Km[l][he]
// ---------------------------------------------------------------------------
__global__ __launch_bounds__(256) void k_scores(
        const float* __restrict__ Qm, const float* __restrict__ Km,
        float* __restrict__ partial) {
    int b = blockIdx.x, sp = blockIdx.y;
    int t = threadIdx.x;
    int h = t >> 6, tl = t & 63;
    int d0 = (tl >> 3) * 4, e0 = (tl & 7) * 4;
    const float* Qb = Qm + ((size_t)b * 4096 + sp * 128) * 128 + h * 32 + d0;
    const float* Kb = Km + ((size_t)b * 4096 + sp * 128) * 128 + h * 32 + e0;
    float acc[4][4] = {};
#pragma unroll 4
    for (int l = 0; l < 128; ++l) {
        float4 q4 = *(const float4*)(Qb + (size_t)l * 128);
        float4 k4 = *(const float4*)(Kb + (size_t)l * 128);
        float q[4] = {q4.x, q4.y, q4.z, q4.w};
        float k[4] = {k4.x, k4.y, k4.z, k4.w};
#pragma unroll
        for (int i = 0; i < 4; ++i)
#pragma unroll
            for (int j = 0; j < 4; ++j) acc[i][j] += q[i] * k[j];
    }
    float* P = partial + ((size_t)(sp * 64 + b * 4 + h)) * 1024;
#pragma unroll
    for (int i = 0; i < 4; ++i)
#pragma unroll
        for (int j = 0; j < 4; ++j)
            P[(d0 + i) * 32 + e0 + j] = acc[i][j];
}

// ---------------------------------------------------------------------------
// K4: fused partial-reduce + softmax + Wc build.  One block per (b,h).
// attn fp32 -> d_out tail; WcT[b][m][h*32+e] = sum_d attn*Wo (bf16).
// ---------------------------------------------------------------------------
__global__ __launch_bounds__(256) void k_attn(
        const float* __restrict__ partial, const ushort* __restrict__ WoB,
        float* __restrict__ attnOut, ushort* __restrict__ WcT) {
    int bh = blockIdx.x; int b = bh >> 2, h = bh & 3;
    __shared__ float aS[1024];
    __shared__ __align__(16) ushort wS[32 * 512];
    int t = threadIdx.x;
    for (int i = t; i < 1024; i += 256) {
        float s = 0.f;
#pragma unroll
        for (int sp = 0; sp < 32; ++sp)
            s += partial[(size_t)(sp * 64 + bh) * 1024 + i];
        aS[i] = s * SCALE_QK;
    }
    for (int i = t; i < 2048; i += 256) {
        int r = i >> 6, c = (i & 63) * 8;
        *(uint4*)&wS[r * 512 + c] = *(const uint4*)&WoB[(size_t)(h * 32 + r) * 512 + c];
    }
    __syncthreads();
    if (t < 32) {
        float m = -1e30f;
#pragma unroll
        for (int e = 0; e < 32; ++e) m = fmaxf(m, aS[t * 32 + e]);
        float p[32]; float sum = 0.f;
#pragma unroll
        for (int e = 0; e < 32; ++e) { p[e] = __expf(aS[t * 32 + e] - m); sum += p[e]; }
        float inv = 1.f / sum;
#pragma unroll
        for (int e = 0; e < 32; ++e) aS[t * 32 + e] = p[e] * inv;
    }
    __syncthreads();
    for (int i = t; i < 1024; i += 256)
        attnOut[(size_t)bh * 1024 + i] = aS[i];
    int e = t & 31, mg = t >> 5;
    for (int mi = 0; mi < 64; ++mi) {
        int m = mg * 64 + mi;
        float acc = 0.f;
#pragma unroll
        for (int d = 0; d < 32; ++d)
            acc += aS[d * 32 + e] * b2f(wS[d * 512 + m]);
        WcT[((size_t)b * 512 + m) * 128 + h * 32 + e] = f2b(acc);
    }
}

// ---------------------------------------------------------------------------
// K5: fused output GEMM + LayerNorm.  Block = 64 rows x 512 cols (full rows).
// x = Vm @ Wc_b + Qm @ Wqo + (bo+bqo); y = LN(x)*gamma+beta -> d_out fp32.
// K=256 concat: k<128 -> (Vm, WcT_b), k>=128 -> (Qm, WqoT).
// 4 waves side-by-side in n; wave computes 64x128 (4m x 8n frags).
// ---------------------------------------------------------------------------
__global__ __launch_bounds__(256) void k_out_ln(
        const ushort* __restrict__ Vm, const ushort* __restrict__ Qm,
        const ushort* __restrict__ WcT, const ushort* __restrict__ WqoT,
        const float* __restrict__ bo, const float* __restrict__ bqo,
        const float* __restrict__ gamma, const float* __restrict__ beta,
        float* __restrict__ Y) {
    __shared__ __align__(16) ushort As[64 * LDSS];
    __shared__ __align__(16) ushort Bs[512 * LDSS];
    __shared__ float sumS[4][64], sumSS[4][64], muA[64], rsA[64];
    const int row0 = blockIdx.x * 64;
    const int b = row0 >> 12;
    const ushort* WcTb = WcT + (size_t)b * 512 * 128;
    const int tid = threadIdx.x;
    const int wid = tid >> 6, lane = tid & 63;
    const int quad = lane >> 4, l16 = lane & 15;
    const int sr = tid >> 2;            // 0..63
    const int sc = (tid & 3) * 8;       // 0,8,16,24

    f32x4 acc[4][8] = {};

    for (int k0 = 0; k0 < 256; k0 += 32) {
        const ushort* Asrc; const ushort* Bsrc; int kk;
        if (k0 < 128) { Asrc = Vm; Bsrc = WcTb; kk = k0; }
        else          { Asrc = Qm; Bsrc = WqoT; kk = k0 - 128; }
        __syncthreads();
        *(uint4*)&As[sr * LDSS + sc] =
            *(const uint4*)&Asrc[(size_t)(row0 + sr) * 128 + kk + sc];
#pragma unroll
        for (int p = 0; p < 8; ++p) {
            int r = sr + p * 64;
            *(uint4*)&Bs[r * LDSS + sc] = *(const uint4*)&Bsrc[(size_t)r * 128 + kk + sc];
        }
        __syncthreads();
        bf16x8 aF[4];
#pragma unroll
        for (int i = 0; i < 4; ++i)
            aF[i] = *reinterpret_cast<const bf16x8*>(&As[(i * 16 + l16) * LDSS + quad * 8]);
#pragma unroll
        for (int j = 0; j < 8; ++j) {
            bf16x8 bF = *reinterpret_cast<const bf16x8*>(
                &Bs[(wid * 128 + j * 16 + l16) * LDSS + quad * 8]);
#pragma unroll
            for (int i = 0; i < 4; ++i)
                acc[i][j] = __builtin_amdgcn_mfma_f32_16x16x32_bf16(aF[i], bF, acc[i][j], 0, 0, 0);
        }
    }

    // bias add + per-lane row partial sums (row = i*16 + quad*4 + r)
    float bv[8];
#pragma unroll
    for (int j = 0; j < 8; ++j) {
        int ncol = wid * 128 + j * 16 + l16;
        bv[j] = bo[ncol] + bqo[ncol];
    }
    float sArr[4][4], ssArr[4][4];
#pragma unroll
    for (int i = 0; i < 4; ++i)
#pragma unroll
        for (int r = 0; r < 4; ++r) {
            float s = 0.f, ss = 0.f;
#pragma unroll
            for (int j = 0; j < 8; ++j) {
                float x = acc[i][j][r] + bv[j];
                s += x; ss += x * x;
            }
            sArr[i][r] = s; ssArr[i][r] = ss;
        }
    // reduce across the 16 lanes of the quad-row group (same rows, diff cols)
#pragma unroll
    for (int off = 1; off < 16; off <<= 1)
#pragma unroll
        for (int i = 0; i < 4; ++i)
#pragma unroll
            for (int r = 0; r < 4; ++r) {
                sArr[i][r]  += __shfl_xor(sArr[i][r],  off, 64);
                ssArr[i][r] += __shfl_xor(ssArr[i][r], off, 64);
            }
    if (l16 == 0) {
#pragma unroll
        for (int i = 0; i < 4; ++i)
#pragma unroll
            for (int r = 0; r < 4; ++r) {
                int row = i * 16 + quad * 4 + r;
                sumS[wid][row]  = sArr[i][r];
                sumSS[wid][row] = ssArr[i][r];
            }
    }
    __syncthreads();
    if (tid < 64) {
        float s = sumS[0][tid] + sumS[1][tid] + sumS[2][tid] + sumS[3][tid];
        float ss = sumSS[0][tid] + sumSS[1][tid] + sumSS[2][tid] + sumSS[3][tid];
        float mu = s * (1.f / 512.f);
        float var = ss * (1.f / 512.f) - mu * mu;
        muA[tid] = mu;
        rsA[tid] = rsqrtf(var + 1e-5f);
    }
    __syncthreads();

    float gj[8], bj[8];
#pragma unroll
    for (int j = 0; j < 8; ++j) {
        int ncol = wid * 128 + j * 16 + l16;
        gj[j] = gamma[ncol]; bj[j] = beta[ncol];
    }
#pragma unroll
    for (int i = 0; i < 4; ++i)
#pragma unroll
        for (int r = 0; r < 4; ++r) {
            int row = i * 16 + quad * 4 + r;
            float mu = muA[row], rstd = rsA[row];
            size_t base = (size_t)(row0 + row) * 512 + wid * 128 + l16;
#pragma unroll
            for (int j = 0; j < 8; ++j) {
                float x = acc[i][j][r] + bv[j];
                Y[base + j * 16] = (x - mu) * rstd * gj[j] + bj[j];
            }
        }
}

// ---------------------------------------------------------------------------
extern "C" void kernel_launch(void* const* d_in, const int* in_sizes, int n_in,
                              void* d_out, int out_size, void* d_ws, size_t ws_size,
                              hipStream_t stream) {
    const float* Qin   = (const float*)d_in[0];
    const float* KVin  = (const float*)d_in[1];
    const float* Wq    = (const float*)d_in[2];
    const float* bq    = (const float*)d_in[3];
    const float* Wk    = (const float*)d_in[4];
    const float* bk    = (const float*)d_in[5];
    const float* Wv    = (const float*)d_in[6];
    const float* bv    = (const float*)d_in[7];
    const float* Wo    = (const float*)d_in[8];
    const float* bo    = (const float*)d_in[9];
    const float* Wqo   = (const float*)d_in[10];
    const float* bqo   = (const float*)d_in[11];
    const float* gamma = (const float*)d_in[12];
    const float* beta  = (const float*)d_in[13];
    float* out = (float*)d_out;           // [y (16*4096*512) | attn (16*4*32*32)]
    float* attnOut = out + 33554432;

    char* ws = (char*)d_ws;
    ushort* WqThi = (ushort*)(ws);
    ushort* WqTlo = (ushort*)(ws + 131072);
    ushort* WkThi = (ushort*)(ws + 262144);
    ushort* WkTlo = (ushort*)(ws + 393216);
    ushort* WvT   = (ushort*)(ws + 524288);
    ushort* WqoT  = (ushort*)(ws + 655360);
    ushort* WoB   = (ushort*)(ws + 786432);
    float*  QmF   = (float*) (ws + 917504);
    float*  KmF   = (float*) (ws + 34471936);
    ushort* QmB   = (ushort*)(ws + 68026368);
    ushort* VmB   = (ushort*)(ws + 84803584);
    float*  part  = (float*) (ws + 101580800);
    ushort* WcT   = (ushort*)(ws + 109969408);
    // total ws use: 112,066,560 bytes

    k_prep<<<1280, 256, 0, stream>>>(Wq, Wk, Wv, Wqo, Wo,
                                     WqThi, WqTlo, WkThi, WkTlo, WvT, WqoT, WoB);
    k_proj_split<<<512, 256, 0, stream>>>(Qin, WqThi, WqTlo, bq, QmF, QmB);
    k_proj_kv<<<512, 256, 0, stream>>>(KVin, WkThi, WkTlo, WvT, bk, bv, KmF, VmB);
    k_scores<<<dim3(16, 32), 256, 0, stream>>>(QmF, KmF, part);
    k_attn<<<64, 256, 0, stream>>>(part, WoB, attnOut, WcT);
    k_out_ln<<<1024, 256, 0, stream>>>(VmB, QmB, WcT, WqoT, bo, bqo, gamma, beta, out);
}